// Round 6
// baseline (161.679 us; speedup 1.0000x reference)
//
#include <hip/hip_runtime.h>

#define BATCH 8
#define S_LEN 2048
#define DDIM 512
#define UDIM 512
#define WIN_L 128
#define WIN_R 128
#define KP 520   // K LDS pitch (f16): 512 + 8, rows 16B aligned
#define VP 40    // V LDS pitch (f16): 32 + 8
#define PP 296   // P LDS pitch (f16)

typedef _Float16 f16;
typedef __attribute__((ext_vector_type(8))) _Float16 f16x8;
typedef __attribute__((ext_vector_type(4))) _Float16 f16x4;
typedef __attribute__((ext_vector_type(4))) float f32x4;

__device__ __forceinline__ void gload_lds16(const void* g, void* l) {
  __builtin_amdgcn_global_load_lds((const __attribute__((address_space(1))) void*)g,
                                   (__attribute__((address_space(3))) void*)l, 16, 0, 0);
}

// ---------------- fused: cast x (fp32->f16) + transpose W ----------------
// blocks [0, 8192): cast; blocks [8192, 8960): W transpose (16 x 16 x 3 tiles)
__global__ void prep(const float* __restrict__ x, const float* __restrict__ Wq,
                     const float* __restrict__ Wk, const float* __restrict__ Wv,
                     f16* __restrict__ xb, f16* __restrict__ WT) {
  __shared__ float t[32][33];
  int bid = blockIdx.x;
  if (bid < 8192) {
    int i = (bid * 256 + threadIdx.x) * 4;
    float4 v = *(const float4*)(x + i);
    f16x4 o;
    o[0] = (f16)v.x; o[1] = (f16)v.y; o[2] = (f16)v.z; o[3] = (f16)v.w;
    *(f16x4*)(xb + i) = o;
  } else {
    int id = bid - 8192;
    int zx = id & 15, zy = (id >> 4) & 15, zz = id >> 8;
    const float* W = zz == 0 ? Wq : (zz == 1 ? Wk : Wv);
    f16* WTz = WT + (size_t)zz * DDIM * UDIM;
    int tx = threadIdx.x & 31, ty = threadIdx.x >> 5;  // 32 x 8
    int n0 = zx * 32, k0 = zy * 32;
    for (int i = 0; i < 4; i++) {
      int r = ty * 4 + i;
      t[r][tx] = W[(size_t)(k0 + r) * UDIM + n0 + tx];
    }
    __syncthreads();
    for (int i = 0; i < 4; i++) {
      int r = ty * 4 + i;
      WTz[(size_t)(n0 + r) * DDIM + k0 + tx] = (f16)t[tx][r];
    }
  }
}

// ---------------- QKV GEMM v2: 128x256 tile, BK=64 (2x32 chunks), 64 MFMA/barrier-pair ----------------
__global__ __launch_bounds__(256, 2) void gemm_qkv(
    const f16* __restrict__ X, const f16* __restrict__ WT,
    const float* __restrict__ bq, const float* __restrict__ bk, const float* __restrict__ bv,
    f16* __restrict__ QKV, f16* __restrict__ VT) {
  int z = blockIdx.z;
  const f16* WTz = WT + (size_t)z * DDIM * UDIM;   // [U][D] layout
  const float* bias = z == 0 ? bq : (z == 1 ? bk : bv);
  f16* out = QKV + (size_t)z * (BATCH * S_LEN) * UDIM;

  __shared__ f16 Al[2][128 * 32];
  __shared__ f16 Bl[2][256 * 32];

  int tid = threadIdx.x, wv = tid >> 6, ln = tid & 63;
  int m0 = blockIdx.x * 128, n0 = blockIdx.y * 256;
  int wm = (wv >> 1) * 64, wn = (wv & 1) * 128;
  int lm = ln & 15, lq = ln >> 4;
  int srow = ln >> 2, scol = (ln & 3) * 8;   // 16 rows x 32 cols per wave-gload

  f32x4 acc[4][8];
#pragma unroll
  for (int mt = 0; mt < 4; mt++)
    for (int nt = 0; nt < 8; nt++)
      for (int r = 0; r < 4; r++) acc[mt][nt][r] = 0.f;

  for (int k0 = 0; k0 < DDIM; k0 += 64) {
#pragma unroll
    for (int c = 0; c < 2; c++) {
#pragma unroll
      for (int half = 0; half < 2; half++) {
        int r0 = half * 64 + wv * 16;  // wave-uniform
        gload_lds16(X + (size_t)(m0 + r0 + srow) * DDIM + k0 + c * 32 + scol, &Al[c][r0 * 32]);
      }
#pragma unroll
      for (int i = 0; i < 4; i++) {
        int r0 = wv * 64 + i * 16;     // wave-uniform
        gload_lds16(WTz + (size_t)(n0 + r0 + srow) * DDIM + k0 + c * 32 + scol, &Bl[c][r0 * 32]);
      }
    }
    __syncthreads();
#pragma unroll
    for (int c = 0; c < 2; c++) {
      f16x8 af[4], bfr[8];
#pragma unroll
      for (int mt = 0; mt < 4; mt++) af[mt] = *(const f16x8*)&Al[c][(wm + mt * 16 + lm) * 32 + lq * 8];
#pragma unroll
      for (int nt = 0; nt < 8; nt++) bfr[nt] = *(const f16x8*)&Bl[c][(wn + nt * 16 + lm) * 32 + lq * 8];
#pragma unroll
      for (int mt = 0; mt < 4; mt++)
#pragma unroll
        for (int nt = 0; nt < 8; nt++)
          acc[mt][nt] = __builtin_amdgcn_mfma_f32_16x16x32_f16(af[mt], bfr[nt], acc[mt][nt], 0, 0, 0);
    }
    __syncthreads();
  }

  if (z == 2) {
#pragma unroll
    for (int mt = 0; mt < 4; mt++)
#pragma unroll
      for (int nt = 0; nt < 8; nt++) {
        int col = n0 + wn + nt * 16 + lm;          // u
        float bv_ = bias[col];
        int row0 = m0 + wm + mt * 16 + lq * 4;     // global s index (r=0)
        int bb = row0 >> 11, ss = row0 & 2047;
        f16x4 o;
        for (int r = 0; r < 4; r++) o[r] = (f16)(acc[mt][nt][r] + bv_);
        *(f16x4*)&VT[((size_t)bb * UDIM + col) * S_LEN + ss] = o;
      }
  } else {
#pragma unroll
    for (int mt = 0; mt < 4; mt++)
#pragma unroll
      for (int nt = 0; nt < 8; nt++) {
        int col = n0 + wn + nt * 16 + lm;
        float bv_ = bias[col];
        for (int r = 0; r < 4; r++) {
          int row = m0 + wm + mt * 16 + lq * 4 + r;
          out[(size_t)row * UDIM + col] = (f16)(acc[mt][nt][r] + bv_);
        }
      }
  }
}

// ---------------- sliding-window attention v6: LDS staging + PV reg-pipeline ----------------
__global__ __launch_bounds__(256, 2) void attn(
    const f16* __restrict__ Q, const f16* __restrict__ K, const f16* __restrict__ VT,
    float* __restrict__ out) {
  __shared__ __align__(16) char ubuf[VP * 512 * 2];  // 40960 B: Kl (33.3KB) / Vl (40KB) union
  __shared__ f16 Pb[32 * PP];                        // 18.9 KB
  __shared__ float wmax[2][32], wsum[2][32];
  f16* Kl = (f16*)ubuf;
  f16* Vl = (f16*)ubuf;

  int tid = threadIdx.x, wv = tid >> 6, ln = tid & 63;
  int lm = ln & 15, lq = ln >> 4;
  int b = blockIdx.x, q0 = blockIdx.y * 32;
  int rh = wv >> 1, kh = wv & 1;        // wave quarter: q-rows rh*16.., keys kh*16..
  const size_t base = (size_t)b * S_LEN;
  const int strip0 = q0 - WIN_L;        // strip keys [strip0, strip0+288)
  const int t_lo = strip0 < 0 ? (-strip0) >> 5 : 0;                 // first live 32-key tile
  int t_hi = (S_LEN - strip0) >> 5; if (t_hi > 9) t_hi = 9;         // one past last live

  // ---- Q fragments (A-operand), invariant ----
  f16x8 qf[16];
  {
    const f16* qrow = Q + (base + q0 + rh * 16 + lm) * (size_t)DDIM + lq * 8;
#pragma unroll
    for (int kk = 0; kk < 16; kk++) qf[kk] = *(const f16x8*)(qrow + kk * 32);
  }

  // ---- S phase: staged key-steps ----
  f32x4 sacc[9];
#pragma unroll
  for (int s = 0; s < 9; s++)
    for (int r = 0; r < 4; r++) sacc[s][r] = 0.f;

#pragma unroll
  for (int s = 0; s < 9; s++) {
    if (s >= t_lo && s < t_hi) {  // block-uniform liveness
      int j0 = strip0 + s * 32;
#pragma unroll
      for (int i = 0; i < 8; i++) {
        int row = wv * 8 + i;
        int key = j0 + row;
        int kc = key < 0 ? 0 : (key > S_LEN - 1 ? S_LEN - 1 : key);
        gload_lds16(K + (base + kc) * (size_t)DDIM + ln * 8, &Kl[row * KP]);
      }
      __syncthreads();
      f32x4 s0, s1;
      for (int r = 0; r < 4; r++) { s0[r] = 0.f; s1[r] = 0.f; }
#pragma unroll
      for (int kk = 0; kk < 16; kk += 2) {
        f16x8 b0 = *(const f16x8*)&Kl[(kh * 16 + lm) * KP + kk * 32 + lq * 8];
        f16x8 b1 = *(const f16x8*)&Kl[(kh * 16 + lm) * KP + (kk + 1) * 32 + lq * 8];
        s0 = __builtin_amdgcn_mfma_f32_16x16x32_f16(qf[kk], b0, s0, 0, 0, 0);
        s1 = __builtin_amdgcn_mfma_f32_16x16x32_f16(qf[kk + 1], b1, s1, 0, 0, 0);
      }
      for (int r = 0; r < 4; r++) sacc[s][r] = s0[r] + s1[r];
      __syncthreads();
    }
  }

  // ---- mask + row max ----
  const float scale = 0.044194173824159216f;  // 1/sqrt(512)
  float mx[4] = {-1e30f, -1e30f, -1e30f, -1e30f};
#pragma unroll
  for (int s = 0; s < 9; s++) {
    int kj = strip0 + s * 32 + kh * 16 + lm;
#pragma unroll
    for (int r = 0; r < 4; r++) {
      int qi = q0 + rh * 16 + lq * 4 + r;
      float v = sacc[s][r] * scale;
      bool ok = (kj >= 0) && (kj < S_LEN) && (kj >= qi - WIN_L) && (kj <= qi + WIN_R);
      v = ok ? v : -1e30f;
      sacc[s][r] = v;
      mx[r] = fmaxf(mx[r], v);
    }
  }
#pragma unroll
  for (int r = 0; r < 4; r++) {
    mx[r] = fmaxf(mx[r], __shfl_xor(mx[r], 1));
    mx[r] = fmaxf(mx[r], __shfl_xor(mx[r], 2));
    mx[r] = fmaxf(mx[r], __shfl_xor(mx[r], 4));
    mx[r] = fmaxf(mx[r], __shfl_xor(mx[r], 8));
  }
  if (lm == 0) {
#pragma unroll
    for (int r = 0; r < 4; r++) wmax[kh][rh * 16 + lq * 4 + r] = mx[r];
  }
  __syncthreads();

  // ---- exp + P park + row sums ----
  float mrow[4], sum[4] = {0.f, 0.f, 0.f, 0.f};
#pragma unroll
  for (int r = 0; r < 4; r++) {
    int row = rh * 16 + lq * 4 + r;
    mrow[r] = fmaxf(wmax[0][row], wmax[1][row]);
  }
#pragma unroll
  for (int s = 0; s < 9; s++) {
#pragma unroll
    for (int r = 0; r < 4; r++) {
      float p = __expf(sacc[s][r] - mrow[r]);
      sum[r] += p;
      Pb[(rh * 16 + lq * 4 + r) * PP + s * 32 + kh * 16 + lm] = (f16)p;
    }
  }
#pragma unroll
  for (int r = 0; r < 4; r++) {
    sum[r] += __shfl_xor(sum[r], 1);
    sum[r] += __shfl_xor(sum[r], 2);
    sum[r] += __shfl_xor(sum[r], 4);
    sum[r] += __shfl_xor(sum[r], 8);
  }
  if (lm == 0) {
#pragma unroll
    for (int r = 0; r < 4; r++) wsum[kh][rh * 16 + lq * 4 + r] = sum[r];
  }
  __syncthreads();  // Pb + sums visible; Kl dead -> Vl may reuse ubuf

  // ---- PV phase: software-pipelined V staging (regs for t+1 load during MFMA of t) ----
  f32x4 oacc[2][8];
#pragma unroll
  for (int mt = 0; mt < 2; mt++)
    for (int nt = 0; nt < 8; nt++)
      for (int r = 0; r < 4; r++) oacc[mt][nt][r] = 0.f;

  int vu = (tid >> 2), vc4 = tid & 3;
  const f16* vsrc = VT + ((size_t)b * UDIM + vu) * S_LEN;
  f16x8 vreg[8];
  {
    int j0 = strip0 + t_lo * 32;
    int key = j0 + vc4 * 8;
    int kc = key < 0 ? 0 : (key > S_LEN - 8 ? S_LEN - 8 : key);
#pragma unroll
    for (int i = 0; i < 8; i++) vreg[i] = *(const f16x8*)(vsrc + (size_t)(i * 64) * S_LEN + kc);
  }

  for (int t = t_lo; t < t_hi; t++) {
#pragma unroll
    for (int i = 0; i < 8; i++) *(f16x8*)&Vl[(i * 64 + vu) * VP + vc4 * 8] = vreg[i];
    __syncthreads();
    if (t + 1 < t_hi) {  // prefetch next slab into regs; overlaps MFMAs below
      int j0 = strip0 + (t + 1) * 32;
      int key = j0 + vc4 * 8;
      int kc = key < 0 ? 0 : (key > S_LEN - 8 ? S_LEN - 8 : key);
#pragma unroll
      for (int i = 0; i < 8; i++) vreg[i] = *(const f16x8*)(vsrc + (size_t)(i * 64) * S_LEN + kc);
    }
    f16x8 pf0 = *(const f16x8*)&Pb[lm * PP + t * 32 + lq * 8];
    f16x8 pf1 = *(const f16x8*)&Pb[(16 + lm) * PP + t * 32 + lq * 8];
#pragma unroll
    for (int nt = 0; nt < 8; nt++) {
      f16x8 vvf = *(const f16x8*)&Vl[(wv * 128 + nt * 16 + lm) * VP + lq * 8];
      oacc[0][nt] = __builtin_amdgcn_mfma_f32_16x16x32_f16(pf0, vvf, oacc[0][nt], 0, 0, 0);
      oacc[1][nt] = __builtin_amdgcn_mfma_f32_16x16x32_f16(pf1, vvf, oacc[1][nt], 0, 0, 0);
    }
    __syncthreads();
  }

  // ---- epilogue: O /= l, fp32 store ----
  float linv[2][4];
#pragma unroll
  for (int mt = 0; mt < 2; mt++)
    for (int r = 0; r < 4; r++) {
      int row = mt * 16 + lq * 4 + r;
      linv[mt][r] = 1.0f / (wsum[0][row] + wsum[1][row]);
    }
#pragma unroll
  for (int mt = 0; mt < 2; mt++)
    for (int nt = 0; nt < 8; nt++)
      for (int r = 0; r < 4; r++) {
        int row = q0 + mt * 16 + lq * 4 + r;
        int col = wv * 128 + nt * 16 + lm;
        out[(base + row) * (size_t)UDIM + col] = oacc[mt][nt][r] * linv[mt][r];
      }
}

extern "C" void kernel_launch(void* const* d_in, const int* in_sizes, int n_in,
                              void* d_out, int out_size, void* d_ws, size_t ws_size,
                              hipStream_t stream) {
  const float* x  = (const float*)d_in[0];
  const float* Wq = (const float*)d_in[1];
  const float* Wk = (const float*)d_in[2];
  const float* Wv = (const float*)d_in[3];
  const float* bq = (const float*)d_in[4];
  const float* bk = (const float*)d_in[5];
  const float* bv = (const float*)d_in[6];
  float* out = (float*)d_out;

  char* ws = (char*)d_ws;
  const size_t XB_BYTES  = (size_t)BATCH * S_LEN * DDIM * 2;       // 16.8 MB
  const size_t WT_BYTES  = (size_t)3 * DDIM * UDIM * 2;            // 1.5 MB
  const size_t QKV_BYTES = (size_t)3 * BATCH * S_LEN * UDIM * 2;   // 50.3 MB
  f16* xb  = (f16*)ws;
  f16* WT  = (f16*)(ws + XB_BYTES);
  f16* QKV = (f16*)(ws + XB_BYTES + WT_BYTES);
  f16* VT  = (f16*)(ws + XB_BYTES + WT_BYTES + QKV_BYTES);

  prep<<<8192 + 768, 256, 0, stream>>>(x, Wq, Wk, Wv, xb, WT);
  gemm_qkv<<<dim3(128, 2, 3), 256, 0, stream>>>(xb, WT, bq, bk, bv, QKV, VT);
  // attn: blockIdx.x = batch so linear id % 8 == batch -> XCD-local K/V in L2
  attn<<<dim3(BATCH, S_LEN / 32), 256, 0, stream>>>(
      QKV, QKV + (size_t)BATCH * S_LEN * UDIM, VT, out);
}

// Round 7
// 155.940 us; speedup vs baseline: 1.0368x; 1.0368x over previous
//
#include <hip/hip_runtime.h>

#define BATCH 8
#define S_LEN 2048
#define DDIM 512
#define UDIM 512
#define WIN_L 128
#define WIN_R 128
#define KP 520   // K LDS pitch (f16): 512 + 8, rows 16B aligned
#define VP 40    // V LDS pitch (f16): 32 + 8
#define PP 296   // P LDS pitch (f16)

typedef _Float16 f16;
typedef __attribute__((ext_vector_type(8))) _Float16 f16x8;
typedef __attribute__((ext_vector_type(4))) _Float16 f16x4;
typedef __attribute__((ext_vector_type(4))) float f32x4;

__device__ __forceinline__ void gload_lds16(const void* g, void* l) {
  __builtin_amdgcn_global_load_lds((const __attribute__((address_space(1))) void*)g,
                                   (__attribute__((address_space(3))) void*)l, 16, 0, 0);
}

// ---------------- fused: cast x (fp32->f16) + transpose W ----------------
__global__ void prep(const float* __restrict__ x, const float* __restrict__ Wq,
                     const float* __restrict__ Wk, const float* __restrict__ Wv,
                     f16* __restrict__ xb, f16* __restrict__ WT) {
  __shared__ float t[32][33];
  int bid = blockIdx.x;
  if (bid < 8192) {
    int i = (bid * 256 + threadIdx.x) * 4;
    float4 v = *(const float4*)(x + i);
    f16x4 o;
    o[0] = (f16)v.x; o[1] = (f16)v.y; o[2] = (f16)v.z; o[3] = (f16)v.w;
    *(f16x4*)(xb + i) = o;
  } else {
    int id = bid - 8192;
    int zx = id & 15, zy = (id >> 4) & 15, zz = id >> 8;
    const float* W = zz == 0 ? Wq : (zz == 1 ? Wk : Wv);
    f16* WTz = WT + (size_t)zz * DDIM * UDIM;
    int tx = threadIdx.x & 31, ty = threadIdx.x >> 5;  // 32 x 8
    int n0 = zx * 32, k0 = zy * 32;
    for (int i = 0; i < 4; i++) {
      int r = ty * 4 + i;
      t[r][tx] = W[(size_t)(k0 + r) * UDIM + n0 + tx];
    }
    __syncthreads();
    for (int i = 0; i < 4; i++) {
      int r = ty * 4 + i;
      WTz[(size_t)(n0 + r) * DDIM + k0 + tx] = (f16)t[tx][r];
    }
  }
}

// ---------------- QKV GEMM: 128x128 tile, BK=64 (2x32 chunks), 3 blocks/CU ----------------
__global__ __launch_bounds__(256, 3) void gemm_qkv(
    const f16* __restrict__ X, const f16* __restrict__ WT,
    const float* __restrict__ bq, const float* __restrict__ bk, const float* __restrict__ bv,
    f16* __restrict__ QKV, f16* __restrict__ VT) {
  int z = blockIdx.z;
  const f16* WTz = WT + (size_t)z * DDIM * UDIM;   // [U][D] layout
  const float* bias = z == 0 ? bq : (z == 1 ? bk : bv);
  f16* out = QKV + (size_t)z * (BATCH * S_LEN) * UDIM;

  __shared__ f16 Al[2][128 * 32];
  __shared__ f16 Bl[2][128 * 32];

  int tid = threadIdx.x, wv = tid >> 6, ln = tid & 63;
  int m0 = blockIdx.x * 128, n0 = blockIdx.y * 128;
  int wm = (wv >> 1) * 64, wn = (wv & 1) * 64;
  int lm = ln & 15, lq = ln >> 4;
  int srow = ln >> 2, scol = (ln & 3) * 8;

  f32x4 acc[4][4];
#pragma unroll
  for (int mt = 0; mt < 4; mt++)
    for (int nt = 0; nt < 4; nt++)
      for (int r = 0; r < 4; r++) acc[mt][nt][r] = 0.f;

  for (int k0 = 0; k0 < DDIM; k0 += 64) {
#pragma unroll
    for (int half = 0; half < 2; half++) {
      int r0 = half * 64 + wv * 16;  // wave-uniform
#pragma unroll
      for (int c = 0; c < 2; c++) {
        gload_lds16(X + (size_t)(m0 + r0 + srow) * DDIM + k0 + c * 32 + scol, &Al[c][r0 * 32]);
        gload_lds16(WTz + (size_t)(n0 + r0 + srow) * DDIM + k0 + c * 32 + scol, &Bl[c][r0 * 32]);
      }
    }
    __syncthreads();
#pragma unroll
    for (int c = 0; c < 2; c++) {
      f16x8 af[4], bfr[4];
#pragma unroll
      for (int mt = 0; mt < 4; mt++) af[mt] = *(const f16x8*)&Al[c][(wm + mt * 16 + lm) * 32 + lq * 8];
#pragma unroll
      for (int nt = 0; nt < 4; nt++) bfr[nt] = *(const f16x8*)&Bl[c][(wn + nt * 16 + lm) * 32 + lq * 8];
#pragma unroll
      for (int mt = 0; mt < 4; mt++)
#pragma unroll
        for (int nt = 0; nt < 4; nt++)
          acc[mt][nt] = __builtin_amdgcn_mfma_f32_16x16x32_f16(af[mt], bfr[nt], acc[mt][nt], 0, 0, 0);
    }
    __syncthreads();
  }

  if (z == 2) {
#pragma unroll
    for (int mt = 0; mt < 4; mt++)
#pragma unroll
      for (int nt = 0; nt < 4; nt++) {
        int col = n0 + wn + nt * 16 + lm;          // u
        float bv_ = bias[col];
        int row0 = m0 + wm + mt * 16 + lq * 4;     // global s index (r=0)
        int bb = row0 >> 11, ss = row0 & 2047;
        f16x4 o;
        for (int r = 0; r < 4; r++) o[r] = (f16)(acc[mt][nt][r] + bv_);
        *(f16x4*)&VT[((size_t)bb * UDIM + col) * S_LEN + ss] = o;
      }
  } else {
#pragma unroll
    for (int mt = 0; mt < 4; mt++)
#pragma unroll
      for (int nt = 0; nt < 4; nt++) {
        int col = n0 + wn + nt * 16 + lm;
        float bv_ = bias[col];
        for (int r = 0; r < 4; r++) {
          int row = m0 + wm + mt * 16 + lq * 4 + r;
          out[(size_t)row * UDIM + col] = (f16)(acc[mt][nt][r] + bv_);
        }
      }
  }
}

// ---------------- sliding-window attention v6: LDS staging + PV reg-pipeline ----------------
__global__ __launch_bounds__(256, 2) void attn(
    const f16* __restrict__ Q, const f16* __restrict__ K, const f16* __restrict__ VT,
    float* __restrict__ out) {
  __shared__ __align__(16) char ubuf[VP * 512 * 2];  // 40960 B: Kl (33.3KB) / Vl (40KB) union
  __shared__ f16 Pb[32 * PP];                        // 18.9 KB
  __shared__ float wmax[2][32], wsum[2][32];
  f16* Kl = (f16*)ubuf;
  f16* Vl = (f16*)ubuf;

  int tid = threadIdx.x, wv = tid >> 6, ln = tid & 63;
  int lm = ln & 15, lq = ln >> 4;
  int b = blockIdx.x, q0 = blockIdx.y * 32;
  int rh = wv >> 1, kh = wv & 1;        // wave quarter: q-rows rh*16.., keys kh*16..
  const size_t base = (size_t)b * S_LEN;
  const int strip0 = q0 - WIN_L;        // strip keys [strip0, strip0+288)
  const int t_lo = strip0 < 0 ? (-strip0) >> 5 : 0;                 // first live 32-key tile
  int t_hi = (S_LEN - strip0) >> 5; if (t_hi > 9) t_hi = 9;         // one past last live

  // ---- Q fragments (A-operand), invariant ----
  f16x8 qf[16];
  {
    const f16* qrow = Q + (base + q0 + rh * 16 + lm) * (size_t)DDIM + lq * 8;
#pragma unroll
    for (int kk = 0; kk < 16; kk++) qf[kk] = *(const f16x8*)(qrow + kk * 32);
  }

  // ---- S phase: staged key-steps ----
  f32x4 sacc[9];
#pragma unroll
  for (int s = 0; s < 9; s++)
    for (int r = 0; r < 4; r++) sacc[s][r] = 0.f;

#pragma unroll
  for (int s = 0; s < 9; s++) {
    if (s >= t_lo && s < t_hi) {  // block-uniform liveness
      int j0 = strip0 + s * 32;
#pragma unroll
      for (int i = 0; i < 8; i++) {
        int row = wv * 8 + i;
        int key = j0 + row;
        int kc = key < 0 ? 0 : (key > S_LEN - 1 ? S_LEN - 1 : key);
        gload_lds16(K + (base + kc) * (size_t)DDIM + ln * 8, &Kl[row * KP]);
      }
      __syncthreads();
      f32x4 s0, s1;
      for (int r = 0; r < 4; r++) { s0[r] = 0.f; s1[r] = 0.f; }
#pragma unroll
      for (int kk = 0; kk < 16; kk += 2) {
        f16x8 b0 = *(const f16x8*)&Kl[(kh * 16 + lm) * KP + kk * 32 + lq * 8];
        f16x8 b1 = *(const f16x8*)&Kl[(kh * 16 + lm) * KP + (kk + 1) * 32 + lq * 8];
        s0 = __builtin_amdgcn_mfma_f32_16x16x32_f16(qf[kk], b0, s0, 0, 0, 0);
        s1 = __builtin_amdgcn_mfma_f32_16x16x32_f16(qf[kk + 1], b1, s1, 0, 0, 0);
      }
      for (int r = 0; r < 4; r++) sacc[s][r] = s0[r] + s1[r];
      __syncthreads();
    }
  }

  // ---- mask + row max ----
  const float scale = 0.044194173824159216f;  // 1/sqrt(512)
  float mx[4] = {-1e30f, -1e30f, -1e30f, -1e30f};
#pragma unroll
  for (int s = 0; s < 9; s++) {
    int kj = strip0 + s * 32 + kh * 16 + lm;
#pragma unroll
    for (int r = 0; r < 4; r++) {
      int qi = q0 + rh * 16 + lq * 4 + r;
      float v = sacc[s][r] * scale;
      bool ok = (kj >= 0) && (kj < S_LEN) && (kj >= qi - WIN_L) && (kj <= qi + WIN_R);
      v = ok ? v : -1e30f;
      sacc[s][r] = v;
      mx[r] = fmaxf(mx[r], v);
    }
  }
#pragma unroll
  for (int r = 0; r < 4; r++) {
    mx[r] = fmaxf(mx[r], __shfl_xor(mx[r], 1));
    mx[r] = fmaxf(mx[r], __shfl_xor(mx[r], 2));
    mx[r] = fmaxf(mx[r], __shfl_xor(mx[r], 4));
    mx[r] = fmaxf(mx[r], __shfl_xor(mx[r], 8));
  }
  if (lm == 0) {
#pragma unroll
    for (int r = 0; r < 4; r++) wmax[kh][rh * 16 + lq * 4 + r] = mx[r];
  }
  __syncthreads();

  // ---- exp + P park + row sums ----
  float mrow[4], sum[4] = {0.f, 0.f, 0.f, 0.f};
#pragma unroll
  for (int r = 0; r < 4; r++) {
    int row = rh * 16 + lq * 4 + r;
    mrow[r] = fmaxf(wmax[0][row], wmax[1][row]);
  }
#pragma unroll
  for (int s = 0; s < 9; s++) {
#pragma unroll
    for (int r = 0; r < 4; r++) {
      float p = __expf(sacc[s][r] - mrow[r]);
      sum[r] += p;
      Pb[(rh * 16 + lq * 4 + r) * PP + s * 32 + kh * 16 + lm] = (f16)p;
    }
  }
#pragma unroll
  for (int r = 0; r < 4; r++) {
    sum[r] += __shfl_xor(sum[r], 1);
    sum[r] += __shfl_xor(sum[r], 2);
    sum[r] += __shfl_xor(sum[r], 4);
    sum[r] += __shfl_xor(sum[r], 8);
  }
  if (lm == 0) {
#pragma unroll
    for (int r = 0; r < 4; r++) wsum[kh][rh * 16 + lq * 4 + r] = sum[r];
  }
  __syncthreads();  // Pb + sums visible; Kl dead -> Vl may reuse ubuf

  // ---- PV phase: software-pipelined V staging (regs for t+1 load during MFMA of t) ----
  f32x4 oacc[2][8];
#pragma unroll
  for (int mt = 0; mt < 2; mt++)
    for (int nt = 0; nt < 8; nt++)
      for (int r = 0; r < 4; r++) oacc[mt][nt][r] = 0.f;

  int vu = (tid >> 2), vc4 = tid & 3;
  const f16* vsrc = VT + ((size_t)b * UDIM + vu) * S_LEN;
  f16x8 vreg[8];
  {
    int j0 = strip0 + t_lo * 32;
    int key = j0 + vc4 * 8;
    int kc = key < 0 ? 0 : (key > S_LEN - 8 ? S_LEN - 8 : key);
#pragma unroll
    for (int i = 0; i < 8; i++) vreg[i] = *(const f16x8*)(vsrc + (size_t)(i * 64) * S_LEN + kc);
  }

  for (int t = t_lo; t < t_hi; t++) {
#pragma unroll
    for (int i = 0; i < 8; i++) *(f16x8*)&Vl[(i * 64 + vu) * VP + vc4 * 8] = vreg[i];
    __syncthreads();
    if (t + 1 < t_hi) {  // prefetch next slab into regs; overlaps MFMAs below
      int j0 = strip0 + (t + 1) * 32;
      int key = j0 + vc4 * 8;
      int kc = key < 0 ? 0 : (key > S_LEN - 8 ? S_LEN - 8 : key);
#pragma unroll
      for (int i = 0; i < 8; i++) vreg[i] = *(const f16x8*)(vsrc + (size_t)(i * 64) * S_LEN + kc);
    }
    f16x8 pf0 = *(const f16x8*)&Pb[lm * PP + t * 32 + lq * 8];
    f16x8 pf1 = *(const f16x8*)&Pb[(16 + lm) * PP + t * 32 + lq * 8];
#pragma unroll
    for (int nt = 0; nt < 8; nt++) {
      f16x8 vvf = *(const f16x8*)&Vl[(wv * 128 + nt * 16 + lm) * VP + lq * 8];
      oacc[0][nt] = __builtin_amdgcn_mfma_f32_16x16x32_f16(pf0, vvf, oacc[0][nt], 0, 0, 0);
      oacc[1][nt] = __builtin_amdgcn_mfma_f32_16x16x32_f16(pf1, vvf, oacc[1][nt], 0, 0, 0);
    }
    __syncthreads();
  }

  // ---- epilogue: O /= l, fp32 store ----
  float linv[2][4];
#pragma unroll
  for (int mt = 0; mt < 2; mt++)
    for (int r = 0; r < 4; r++) {
      int row = mt * 16 + lq * 4 + r;
      linv[mt][r] = 1.0f / (wsum[0][row] + wsum[1][row]);
    }
#pragma unroll
  for (int mt = 0; mt < 2; mt++)
    for (int nt = 0; nt < 8; nt++)
      for (int r = 0; r < 4; r++) {
        int row = q0 + mt * 16 + lq * 4 + r;
        int col = wv * 128 + nt * 16 + lm;
        out[(base + row) * (size_t)UDIM + col] = oacc[mt][nt][r] * linv[mt][r];
      }
}

extern "C" void kernel_launch(void* const* d_in, const int* in_sizes, int n_in,
                              void* d_out, int out_size, void* d_ws, size_t ws_size,
                              hipStream_t stream) {
  const float* x  = (const float*)d_in[0];
  const float* Wq = (const float*)d_in[1];
  const float* Wk = (const float*)d_in[2];
  const float* Wv = (const float*)d_in[3];
  const float* bq = (const float*)d_in[4];
  const float* bk = (const float*)d_in[5];
  const float* bv = (const float*)d_in[6];
  float* out = (float*)d_out;

  char* ws = (char*)d_ws;
  const size_t XB_BYTES  = (size_t)BATCH * S_LEN * DDIM * 2;       // 16.8 MB
  const size_t WT_BYTES  = (size_t)3 * DDIM * UDIM * 2;            // 1.5 MB
  const size_t QKV_BYTES = (size_t)3 * BATCH * S_LEN * UDIM * 2;   // 50.3 MB
  f16* xb  = (f16*)ws;
  f16* WT  = (f16*)(ws + XB_BYTES);
  f16* QKV = (f16*)(ws + XB_BYTES + WT_BYTES);
  f16* VT  = (f16*)(ws + XB_BYTES + WT_BYTES + QKV_BYTES);

  prep<<<8192 + 768, 256, 0, stream>>>(x, Wq, Wk, Wv, xb, WT);
  gemm_qkv<<<dim3(128, 4, 3), 256, 0, stream>>>(xb, WT, bq, bk, bv, QKV, VT);
  // attn: blockIdx.x = batch so linear id % 8 == batch -> XCD-local K/V in L2
  attn<<<dim3(BATCH, S_LEN / 32), 256, 0, stream>>>(
      QKV, QKV + (size_t)BATCH * S_LEN * UDIM, VT, out);
}

// Round 8
// 153.723 us; speedup vs baseline: 1.0518x; 1.0144x over previous
//
#include <hip/hip_runtime.h>

#define BATCH 8
#define S_LEN 2048
#define DDIM 512
#define UDIM 512
#define WIN_L 128
#define WIN_R 128
#define KP 520   // K LDS pitch (f16): 512 + 8, rows 16B aligned
#define VP 40    // V LDS pitch (f16): 32 + 8
#define PP 296   // P LDS pitch (f16)

typedef _Float16 f16;
typedef __attribute__((ext_vector_type(8))) _Float16 f16x8;
typedef __attribute__((ext_vector_type(4))) _Float16 f16x4;
typedef __attribute__((ext_vector_type(4))) float f32x4;

__device__ __forceinline__ void gload_lds16(const void* g, void* l) {
  __builtin_amdgcn_global_load_lds((const __attribute__((address_space(1))) void*)g,
                                   (__attribute__((address_space(3))) void*)l, 16, 0, 0);
}

// ---------------- prep: transpose W [D][U] fp32 -> WT [U][D] f16 (x-cast now fused into gemm) ----------------
__global__ void prep(const float* __restrict__ Wq, const float* __restrict__ Wk,
                     const float* __restrict__ Wv, f16* __restrict__ WT) {
  __shared__ float t[32][33];
  int id = blockIdx.x;
  int zx = id & 15, zy = (id >> 4) & 15, zz = id >> 8;
  const float* W = zz == 0 ? Wq : (zz == 1 ? Wk : Wv);
  f16* WTz = WT + (size_t)zz * DDIM * UDIM;
  int tx = threadIdx.x & 31, ty = threadIdx.x >> 5;  // 32 x 8
  int n0 = zx * 32, k0 = zy * 32;
  for (int i = 0; i < 4; i++) {
    int r = ty * 4 + i;
    t[r][tx] = W[(size_t)(k0 + r) * UDIM + n0 + tx];
  }
  __syncthreads();
  for (int i = 0; i < 4; i++) {
    int r = ty * 4 + i;
    WTz[(size_t)(n0 + r) * DDIM + k0 + tx] = (f16)t[tx][r];
  }
}

// ---------------- QKV GEMM v3: fp32 A read + in-kernel cast; 128x128, BK=64; XCD-swizzled 1D grid ----------------
// grid = 1536 1D. xcd = g&7; all 12 (ny,z) blocks for one m-block share an XCD -> x rows L2-resident.
// Also: m_blk>>4 == batch == xcd, so batch b's QKV lands in XCD b's L2, where attn (blockIdx.x=b) reads it.
__global__ __launch_bounds__(256, 3) void gemm_qkv(
    const float* __restrict__ X32, const f16* __restrict__ WT,
    const float* __restrict__ bq, const float* __restrict__ bk, const float* __restrict__ bv,
    f16* __restrict__ QKV, f16* __restrict__ VT) {
  int g = blockIdx.x;
  int xcd = g & 7, j = g >> 3;           // j in [0,192)
  int m_blk = xcd * 16 + (j & 15);       // 0..127
  int rest = j >> 4;                     // 0..11
  int ny = rest & 3, z = rest >> 2;      // ny 0..3, z 0..2

  const f16* WTz = WT + (size_t)z * DDIM * UDIM;   // [U][D] layout
  const float* bias = z == 0 ? bq : (z == 1 ? bk : bv);
  f16* out = QKV + (size_t)z * (BATCH * S_LEN) * UDIM;

  __shared__ f16 Al[2][128 * 32];
  __shared__ f16 Bl[2][128 * 32];

  int tid = threadIdx.x, wv = tid >> 6, ln = tid & 63;
  int m0 = m_blk * 128, n0 = ny * 128;
  int wm = (wv >> 1) * 64, wn = (wv & 1) * 64;
  int lm = ln & 15, lq = ln >> 4;
  int srow = ln >> 2, scol = (ln & 3) * 8;   // B-staging: 16 rows x 32 cols per gload
  int arow = ln >> 2, acol = (ln & 3) * 8;   // A-staging: same footprint via VGPR+cvt

  f32x4 acc[4][4];
#pragma unroll
  for (int mt = 0; mt < 4; mt++)
    for (int nt = 0; nt < 4; nt++)
      for (int r = 0; r < 4; r++) acc[mt][nt][r] = 0.f;

  // A-prefetch registers: [chunk c][row-half h][2x float4]
  float4 ap[2][2][2];
#pragma unroll
  for (int c = 0; c < 2; c++)
#pragma unroll
    for (int h = 0; h < 2; h++) {
      const float* p = X32 + (size_t)(m0 + wv * 32 + h * 16 + arow) * DDIM + c * 32 + (ln & 3) * 8;
      ap[c][h][0] = *(const float4*)p;
      ap[c][h][1] = *(const float4*)(p + 4);
    }

  for (int k0 = 0; k0 < DDIM; k0 += 64) {
    // ---- A: cvt regs -> f16 LDS ----
#pragma unroll
    for (int c = 0; c < 2; c++)
#pragma unroll
      for (int h = 0; h < 2; h++) {
        float4 p0 = ap[c][h][0], p1 = ap[c][h][1];
        f16x8 o;
        o[0] = (f16)p0.x; o[1] = (f16)p0.y; o[2] = (f16)p0.z; o[3] = (f16)p0.w;
        o[4] = (f16)p1.x; o[5] = (f16)p1.y; o[6] = (f16)p1.z; o[7] = (f16)p1.w;
        *(f16x8*)&Al[c][(wv * 32 + h * 16 + arow) * 32 + acol] = o;
      }
    // ---- B: async global->LDS ----
#pragma unroll
    for (int half = 0; half < 2; half++) {
      int r0 = half * 64 + wv * 16;  // wave-uniform
#pragma unroll
      for (int c = 0; c < 2; c++)
        gload_lds16(WTz + (size_t)(n0 + r0 + srow) * DDIM + k0 + c * 32 + scol, &Bl[c][r0 * 32]);
    }
    __syncthreads();

    // ---- prefetch next A (overlaps MFMAs below) ----
    if (k0 + 64 < DDIM) {
#pragma unroll
      for (int c = 0; c < 2; c++)
#pragma unroll
        for (int h = 0; h < 2; h++) {
          const float* p = X32 + (size_t)(m0 + wv * 32 + h * 16 + arow) * DDIM + (k0 + 64) + c * 32 + (ln & 3) * 8;
          ap[c][h][0] = *(const float4*)p;
          ap[c][h][1] = *(const float4*)(p + 4);
        }
    }

#pragma unroll
    for (int c = 0; c < 2; c++) {
      f16x8 af[4], bfr[4];
#pragma unroll
      for (int mt = 0; mt < 4; mt++) af[mt] = *(const f16x8*)&Al[c][(wm + mt * 16 + lm) * 32 + lq * 8];
#pragma unroll
      for (int nt = 0; nt < 4; nt++) bfr[nt] = *(const f16x8*)&Bl[c][(wn + nt * 16 + lm) * 32 + lq * 8];
#pragma unroll
      for (int mt = 0; mt < 4; mt++)
#pragma unroll
        for (int nt = 0; nt < 4; nt++)
          acc[mt][nt] = __builtin_amdgcn_mfma_f32_16x16x32_f16(af[mt], bfr[nt], acc[mt][nt], 0, 0, 0);
    }
    __syncthreads();
  }

  if (z == 2) {
#pragma unroll
    for (int mt = 0; mt < 4; mt++)
#pragma unroll
      for (int nt = 0; nt < 4; nt++) {
        int col = n0 + wn + nt * 16 + lm;          // u
        float bv_ = bias[col];
        int row0 = m0 + wm + mt * 16 + lq * 4;     // global s index (r=0)
        int bb = row0 >> 11, ss = row0 & 2047;
        f16x4 o;
        for (int r = 0; r < 4; r++) o[r] = (f16)(acc[mt][nt][r] + bv_);
        *(f16x4*)&VT[((size_t)bb * UDIM + col) * S_LEN + ss] = o;
      }
  } else {
#pragma unroll
    for (int mt = 0; mt < 4; mt++)
#pragma unroll
      for (int nt = 0; nt < 4; nt++) {
        int col = n0 + wn + nt * 16 + lm;
        float bv_ = bias[col];
        for (int r = 0; r < 4; r++) {
          int row = m0 + wm + mt * 16 + lq * 4 + r;
          out[(size_t)row * UDIM + col] = (f16)(acc[mt][nt][r] + bv_);
        }
      }
  }
}

// ---------------- sliding-window attention v6: LDS staging + PV reg-pipeline (unchanged) ----------------
__global__ __launch_bounds__(256, 2) void attn(
    const f16* __restrict__ Q, const f16* __restrict__ K, const f16* __restrict__ VT,
    float* __restrict__ out) {
  __shared__ __align__(16) char ubuf[VP * 512 * 2];  // 40960 B: Kl (33.3KB) / Vl (40KB) union
  __shared__ f16 Pb[32 * PP];                        // 18.9 KB
  __shared__ float wmax[2][32], wsum[2][32];
  f16* Kl = (f16*)ubuf;
  f16* Vl = (f16*)ubuf;

  int tid = threadIdx.x, wv = tid >> 6, ln = tid & 63;
  int lm = ln & 15, lq = ln >> 4;
  int b = blockIdx.x, q0 = blockIdx.y * 32;
  int rh = wv >> 1, kh = wv & 1;        // wave quarter: q-rows rh*16.., keys kh*16..
  const size_t base = (size_t)b * S_LEN;
  const int strip0 = q0 - WIN_L;        // strip keys [strip0, strip0+288)
  const int t_lo = strip0 < 0 ? (-strip0) >> 5 : 0;                 // first live 32-key tile
  int t_hi = (S_LEN - strip0) >> 5; if (t_hi > 9) t_hi = 9;         // one past last live

  // ---- Q fragments (A-operand), invariant ----
  f16x8 qf[16];
  {
    const f16* qrow = Q + (base + q0 + rh * 16 + lm) * (size_t)DDIM + lq * 8;
#pragma unroll
    for (int kk = 0; kk < 16; kk++) qf[kk] = *(const f16x8*)(qrow + kk * 32);
  }

  // ---- S phase: staged key-steps ----
  f32x4 sacc[9];
#pragma unroll
  for (int s = 0; s < 9; s++)
    for (int r = 0; r < 4; r++) sacc[s][r] = 0.f;

#pragma unroll
  for (int s = 0; s < 9; s++) {
    if (s >= t_lo && s < t_hi) {  // block-uniform liveness
      int j0 = strip0 + s * 32;
#pragma unroll
      for (int i = 0; i < 8; i++) {
        int row = wv * 8 + i;
        int key = j0 + row;
        int kc = key < 0 ? 0 : (key > S_LEN - 1 ? S_LEN - 1 : key);
        gload_lds16(K + (base + kc) * (size_t)DDIM + ln * 8, &Kl[row * KP]);
      }
      __syncthreads();
      f32x4 s0, s1;
      for (int r = 0; r < 4; r++) { s0[r] = 0.f; s1[r] = 0.f; }
#pragma unroll
      for (int kk = 0; kk < 16; kk += 2) {
        f16x8 b0 = *(const f16x8*)&Kl[(kh * 16 + lm) * KP + kk * 32 + lq * 8];
        f16x8 b1 = *(const f16x8*)&Kl[(kh * 16 + lm) * KP + (kk + 1) * 32 + lq * 8];
        s0 = __builtin_amdgcn_mfma_f32_16x16x32_f16(qf[kk], b0, s0, 0, 0, 0);
        s1 = __builtin_amdgcn_mfma_f32_16x16x32_f16(qf[kk + 1], b1, s1, 0, 0, 0);
      }
      for (int r = 0; r < 4; r++) sacc[s][r] = s0[r] + s1[r];
      __syncthreads();
    }
  }

  // ---- mask + row max ----
  const float scale = 0.044194173824159216f;  // 1/sqrt(512)
  float mx[4] = {-1e30f, -1e30f, -1e30f, -1e30f};
#pragma unroll
  for (int s = 0; s < 9; s++) {
    int kj = strip0 + s * 32 + kh * 16 + lm;
#pragma unroll
    for (int r = 0; r < 4; r++) {
      int qi = q0 + rh * 16 + lq * 4 + r;
      float v = sacc[s][r] * scale;
      bool ok = (kj >= 0) && (kj < S_LEN) && (kj >= qi - WIN_L) && (kj <= qi + WIN_R);
      v = ok ? v : -1e30f;
      sacc[s][r] = v;
      mx[r] = fmaxf(mx[r], v);
    }
  }
#pragma unroll
  for (int r = 0; r < 4; r++) {
    mx[r] = fmaxf(mx[r], __shfl_xor(mx[r], 1));
    mx[r] = fmaxf(mx[r], __shfl_xor(mx[r], 2));
    mx[r] = fmaxf(mx[r], __shfl_xor(mx[r], 4));
    mx[r] = fmaxf(mx[r], __shfl_xor(mx[r], 8));
  }
  if (lm == 0) {
#pragma unroll
    for (int r = 0; r < 4; r++) wmax[kh][rh * 16 + lq * 4 + r] = mx[r];
  }
  __syncthreads();

  // ---- exp + P park + row sums ----
  float mrow[4], sum[4] = {0.f, 0.f, 0.f, 0.f};
#pragma unroll
  for (int r = 0; r < 4; r++) {
    int row = rh * 16 + lq * 4 + r;
    mrow[r] = fmaxf(wmax[0][row], wmax[1][row]);
  }
#pragma unroll
  for (int s = 0; s < 9; s++) {
#pragma unroll
    for (int r = 0; r < 4; r++) {
      float p = __expf(sacc[s][r] - mrow[r]);
      sum[r] += p;
      Pb[(rh * 16 + lq * 4 + r) * PP + s * 32 + kh * 16 + lm] = (f16)p;
    }
  }
#pragma unroll
  for (int r = 0; r < 4; r++) {
    sum[r] += __shfl_xor(sum[r], 1);
    sum[r] += __shfl_xor(sum[r], 2);
    sum[r] += __shfl_xor(sum[r], 4);
    sum[r] += __shfl_xor(sum[r], 8);
  }
  if (lm == 0) {
#pragma unroll
    for (int r = 0; r < 4; r++) wsum[kh][rh * 16 + lq * 4 + r] = sum[r];
  }
  __syncthreads();  // Pb + sums visible; Kl dead -> Vl may reuse ubuf

  // ---- PV phase: software-pipelined V staging ----
  f32x4 oacc[2][8];
#pragma unroll
  for (int mt = 0; mt < 2; mt++)
    for (int nt = 0; nt < 8; nt++)
      for (int r = 0; r < 4; r++) oacc[mt][nt][r] = 0.f;

  int vu = (tid >> 2), vc4 = tid & 3;
  const f16* vsrc = VT + ((size_t)b * UDIM + vu) * S_LEN;
  f16x8 vreg[8];
  {
    int j0 = strip0 + t_lo * 32;
    int key = j0 + vc4 * 8;
    int kc = key < 0 ? 0 : (key > S_LEN - 8 ? S_LEN - 8 : key);
#pragma unroll
    for (int i = 0; i < 8; i++) vreg[i] = *(const f16x8*)(vsrc + (size_t)(i * 64) * S_LEN + kc);
  }

  for (int t = t_lo; t < t_hi; t++) {
#pragma unroll
    for (int i = 0; i < 8; i++) *(f16x8*)&Vl[(i * 64 + vu) * VP + vc4 * 8] = vreg[i];
    __syncthreads();
    if (t + 1 < t_hi) {  // prefetch next slab into regs; overlaps MFMAs below
      int j0 = strip0 + (t + 1) * 32;
      int key = j0 + vc4 * 8;
      int kc = key < 0 ? 0 : (key > S_LEN - 8 ? S_LEN - 8 : key);
#pragma unroll
      for (int i = 0; i < 8; i++) vreg[i] = *(const f16x8*)(vsrc + (size_t)(i * 64) * S_LEN + kc);
    }
    f16x8 pf0 = *(const f16x8*)&Pb[lm * PP + t * 32 + lq * 8];
    f16x8 pf1 = *(const f16x8*)&Pb[(16 + lm) * PP + t * 32 + lq * 8];
#pragma unroll
    for (int nt = 0; nt < 8; nt++) {
      f16x8 vvf = *(const f16x8*)&Vl[(wv * 128 + nt * 16 + lm) * VP + lq * 8];
      oacc[0][nt] = __builtin_amdgcn_mfma_f32_16x16x32_f16(pf0, vvf, oacc[0][nt], 0, 0, 0);
      oacc[1][nt] = __builtin_amdgcn_mfma_f32_16x16x32_f16(pf1, vvf, oacc[1][nt], 0, 0, 0);
    }
    __syncthreads();
  }

  // ---- epilogue: O /= l, fp32 store ----
  float linv[2][4];
#pragma unroll
  for (int mt = 0; mt < 2; mt++)
    for (int r = 0; r < 4; r++) {
      int row = mt * 16 + lq * 4 + r;
      linv[mt][r] = 1.0f / (wsum[0][row] + wsum[1][row]);
    }
#pragma unroll
  for (int mt = 0; mt < 2; mt++)
    for (int nt = 0; nt < 8; nt++)
      for (int r = 0; r < 4; r++) {
        int row = q0 + mt * 16 + lq * 4 + r;
        int col = wv * 128 + nt * 16 + lm;
        out[(base + row) * (size_t)UDIM + col] = oacc[mt][nt][r] * linv[mt][r];
      }
}

extern "C" void kernel_launch(void* const* d_in, const int* in_sizes, int n_in,
                              void* d_out, int out_size, void* d_ws, size_t ws_size,
                              hipStream_t stream) {
  const float* x  = (const float*)d_in[0];
  const float* Wq = (const float*)d_in[1];
  const float* Wk = (const float*)d_in[2];
  const float* Wv = (const float*)d_in[3];
  const float* bq = (const float*)d_in[4];
  const float* bk = (const float*)d_in[5];
  const float* bv = (const float*)d_in[6];
  float* out = (float*)d_out;

  char* ws = (char*)d_ws;
  const size_t WT_BYTES  = (size_t)3 * DDIM * UDIM * 2;            // 1.5 MB
  const size_t QKV_BYTES = (size_t)3 * BATCH * S_LEN * UDIM * 2;   // 50.3 MB
  f16* WT  = (f16*)ws;
  f16* QKV = (f16*)(ws + WT_BYTES);
  f16* VT  = (f16*)(ws + WT_BYTES + QKV_BYTES);

  prep<<<768, 256, 0, stream>>>(Wq, Wk, Wv, WT);
  gemm_qkv<<<1536, 256, 0, stream>>>(x, WT, bq, bk, bv, QKV, VT);
  // attn: blockIdx.x = batch so linear id % 8 == batch -> XCD-local K/V in L2
  attn<<<dim3(BATCH, S_LEN / 32), 256, 0, stream>>>(
      QKV, QKV + (size_t)BATCH * S_LEN * UDIM, VT, out);
}